// Round 7
// baseline (244.972 us; speedup 1.0000x reference)
//
#include <hip/hip_runtime.h>
#include <hip/hip_bf16.h>

// Problem constants
#define NN   4096      // nodes
#define FIN  1433      // input features
#define KPAD 1536      // padded K for GEMM1 (12 * 128)
#define NH   8         // heads
#define ND   64        // hidden per head
#define CD   512       // NH*ND

typedef float f32x4 __attribute__((ext_vector_type(4)));
typedef short s16x8 __attribute__((ext_vector_type(8)));   // 8 bf16

#define MFMA16(a, b, c) __builtin_amdgcn_mfma_f32_16x16x32_bf16((a), (b), (c), 0, 0, 0)

__device__ __forceinline__ void gload_lds16(const void* g, void* l) {
  __builtin_amdgcn_global_load_lds((const __attribute__((address_space(1))) void*)g,
                                   (__attribute__((address_space(3))) void*)l, 16, 0, 0);
}

__device__ __forceinline__ ushort f2bf(float x) {
  __hip_bfloat16 b = __float2bfloat16(x);
  ushort u;
  __builtin_memcpy(&u, &b, 2);
  return u;
}

// ---------------------------------------------------------------------------
// Kernel 1: f32 -> bf16 cast with K padding (1433 -> 1536, zero fill).
// 8 elems/thread, one 16B store (G13). Verified working.
// ---------------------------------------------------------------------------
__global__ void castpad_kernel(const float* __restrict__ src, ushort* __restrict__ dst,
                               int rows, int kin, int kout) {
  int i = blockIdx.x * blockDim.x + threadIdx.x;   // one 8-elem group
  int kg = kout >> 3;
  int total = rows * kg;
  if (i >= total) return;
  int r  = i / kg;
  int k0 = (i - r * kg) << 3;
  s16x8 v;
#pragma unroll
  for (int j = 0; j < 8; ++j) {
    int k = k0 + j;
    float f = (k < kin) ? src[(size_t)r * kin + k] : 0.0f;
    v[j] = (short)f2bf(f);
  }
  *reinterpret_cast<s16x8*>(&dst[(size_t)r * kout + k0]) = v;
}

// ---------------------------------------------------------------------------
// Kernel 2: GEMM1  g = vertex @ W_vert^T   (NT, both K-contiguous)
// Round-6 counters (inferred): old x-major grid round-robined same-A-row
// blocks across XCDs -> A (12.6 MB) re-fetched per-XCD from HBM (~100 MB).
// Now 1-D grid, XCD ROW-BAND decode: XCD x = b&7 owns row-tiles x*8..x*8+7
// for all 8 col-tiles -> per-XCD working set = A-band 1.57 MB + B 1.5 MB,
// fits its 4 MB L2. BK=128 double-buffered as before.
// ---------------------------------------------------------------------------
__global__ __launch_bounds__(256, 2) void gemm1_kernel(const ushort* __restrict__ A,
                                                       const ushort* __restrict__ B,
                                                       ushort* __restrict__ G) {
  __shared__ ushort As[2][64][128];   // 16 KB per buf
  __shared__ ushort Bs[2][64][128];
  const int tid  = threadIdx.x;
  const int lane = tid & 63;
  const int w    = tid >> 6;       // wave 0..3
  const int wr   = w >> 1, wc = w & 1;

  // XCD row-band decode: hardware assigns block b -> XCD b%8.
  const int b    = blockIdx.x;          // 0..511
  const int x    = b & 7;               // XCD
  const int slot = b >> 3;              // 0..63
  const int by   = x * 8 + (slot >> 3); // row tile 0..63
  const int bx   = slot & 7;            // col tile 0..7
  const int row0 = by * 64;             // over NN
  const int col0 = bx * 64;             // over CD

  f32x4 acc[2][2] = {};

  auto stage = [&](int buf, int k0) {
#pragma unroll
    for (int j = 0; j < 4; ++j) {
      int ci = (w * 4 + j) * 64 + lane;
      int r  = ci >> 4;
      int cp = ci & 15;
      int gc = cp ^ (r & 7);
      gload_lds16(A + (size_t)(row0 + r) * KPAD + k0 + gc * 8,
                  &As[buf][0][0] + (size_t)(w * 4 + j) * 512);
      gload_lds16(B + (size_t)(col0 + r) * KPAD + k0 + gc * 8,
                  &Bs[buf][0][0] + (size_t)(w * 4 + j) * 512);
    }
  };

  stage(0, 0);
  __syncthreads();
  int cur = 0;

  for (int k0 = 0; k0 < KPAD; k0 += 128) {
    if (k0 + 128 < KPAD) stage(cur ^ 1, k0 + 128);   // prefetch next K-tile
#pragma unroll
    for (int kk = 0; kk < 4; ++kk) {                 // 4 x K=32 sub-steps
      int kq = kk * 4 + (lane >> 4);                 // chunk 0..15 within row
      s16x8 af[2], bfv[2];
#pragma unroll
      for (int f = 0; f < 2; ++f) {
        int ar = wr * 32 + f * 16 + (lane & 15);
        af[f]  = *reinterpret_cast<const s16x8*>(&As[cur][ar][(kq ^ (ar & 7)) * 8]);
        int br = wc * 32 + f * 16 + (lane & 15);
        bfv[f] = *reinterpret_cast<const s16x8*>(&Bs[cur][br][(kq ^ (br & 7)) * 8]);
      }
#pragma unroll
      for (int fi = 0; fi < 2; ++fi)
#pragma unroll
        for (int fj = 0; fj < 2; ++fj)
          acc[fi][fj] = MFMA16(af[fi], bfv[fj], acc[fi][fj]);
    }
    __syncthreads();        // joins waves + drains prefetch DMA writes
    cur ^= 1;
  }

  // epilogue: C/D layout col=lane&15, row=(lane>>4)*4+reg  [m89-verified]
#pragma unroll
  for (int fi = 0; fi < 2; ++fi)
#pragma unroll
    for (int fj = 0; fj < 2; ++fj)
#pragma unroll
      for (int r = 0; r < 4; ++r) {
        int gr = row0 + wr * 32 + fi * 16 + (lane >> 4) * 4 + r;
        int gcol = col0 + wc * 32 + fj * 16 + (lane & 15);
        G[(size_t)gr * CD + gcol] = f2bf(acc[fi][fj][r]);
      }
}

// ---------------------------------------------------------------------------
// Kernel 3: fused per-head Gram + head-mix + leaky-relu + head-sum.
// Round-6 counters: WRITE 120.7 MB (1.8x amplification: 64B-segment direct
// writes evicted as partial lines) and FETCH 60 MB (G=4MB re-fetched 15x:
// output stream thrashed per-XCD L2) -> 82 us of stall (MfmaUtil 0.18%).
// v3: (a) ALL output writes via LDS staging -> 1KB-contiguous float4
// NONTEMPORAL stores (full lines, no L2 allocation -> G stays resident);
// (b) 2-head sub-stages (4 x 16 KB), double-buffered: stage(s+1) overlaps
// compute(s). Occupancy is hard-capped at 2 blk/CU by the 128-float acc.
// ---------------------------------------------------------------------------
__global__ __launch_bounds__(256, 2) void gram_kernel(const ushort* __restrict__ G,
                                                      const float* __restrict__ Wattn,
                                                      float* __restrict__ out) {
  // ---- triangular tile decode with XCD swizzle ----
  const int nwg = (NN / 64) * (NN / 64 + 1) / 2;   // 2080
  const int cpx = nwg / 8;                          // 260
  int b = blockIdx.x;
  int t = (b % 8) * cpx + (b / 8);                  // bijective: 2080 % 8 == 0
  int bi = (int)((129.0f - sqrtf(16641.0f - 8.0f * (float)t)) * 0.5f);
  while ((129 * (bi + 1) - (bi + 1) * (bi + 1)) / 2 <= t) ++bi;
  while ((129 * bi - bi * bi) / 2 > t) --bi;
  const int bj = bi + (t - (129 * bi - bi * bi) / 2);
  const int ri0 = bi * 64, ci0 = bj * 64;

  __shared__ union LdsU {
    struct { ushort A[2][64][128]; ushort B[2][64][128]; } s;  // 4 x 16 KB
    float t[64][65];           // write staging (reuses dead bufs)
  } lds;
  __shared__ float sW[8][8];

  const int tid  = threadIdx.x;
  const int lane = tid & 63;
  const int w    = tid >> 6;
  const int wr   = w >> 1, wc = w & 1;

  if (tid < 64) sW[tid >> 3][tid & 7] = Wattn[tid];

  f32x4 acc[8][2][2] = {};   // [head][fi][fj] — fully static indexing

  // stage heads 2s,2s+1 into buf: per operand 64 rows x 128 cols bf16
  // = 16 KB = 1024 chunks; 4 instr/thread/operand. Row = 16 chunks;
  // fetch global chunk cp^(r&7) (involution, stays within row).
  auto stage = [&](int buf, int s) {
#pragma unroll
    for (int j = 0; j < 4; ++j) {
      int ci = (w * 4 + j) * 64 + lane;   // 0..1023
      int r  = ci >> 4;
      int cp = ci & 15;
      int gc = cp ^ (r & 7);
      gload_lds16(G + (size_t)(ri0 + r) * CD + s * 128 + gc * 8,
                  &lds.s.A[buf][0][0] + (size_t)(w * 4 + j) * 512);
      gload_lds16(G + (size_t)(ci0 + r) * CD + s * 128 + gc * 8,
                  &lds.s.B[buf][0][0] + (size_t)(w * 4 + j) * 512);
    }
  };

  // compute heads 2s, 2s+1 from buf
  auto compute = [&](int buf, int s) {
#pragma unroll
    for (int hh = 0; hh < 2; ++hh) {
#pragma unroll
      for (int kk = 0; kk < 2; ++kk) {
        int kq = hh * 8 + kk * 4 + (lane >> 4);   // chunk 0..15 within row
        s16x8 af[2], bfv[2];
#pragma unroll
        for (int f = 0; f < 2; ++f) {
          int ar = wr * 32 + f * 16 + (lane & 15);
          af[f]  = *reinterpret_cast<const s16x8*>(
                     &lds.s.A[buf][ar][(kq ^ (ar & 7)) * 8]);
          int br = wc * 32 + f * 16 + (lane & 15);
          bfv[f] = *reinterpret_cast<const s16x8*>(
                     &lds.s.B[buf][br][(kq ^ (br & 7)) * 8]);
        }
        int h = s * 2 + hh;
#pragma unroll
        for (int fi = 0; fi < 2; ++fi)
#pragma unroll
          for (int fj = 0; fj < 2; ++fj)
            acc[h][fi][fj] = MFMA16(af[fi], bfv[fj], acc[h][fi][fj]);
      }
    }
  };

  stage(0, 0);
  __syncthreads();
  int cur = 0;
#pragma unroll
  for (int s = 0; s < 4; ++s) {
    if (s < 3) stage(cur ^ 1, s + 1);   // prefetch overlaps compute
    compute(cur, s);
    __syncthreads();                    // joins + drains prefetch DMA
    cur ^= 1;
  }

  // Epilogue: z_g = sum_h gram_h * W[g][h];  out = sum_g lrelu(z_g)
  float o[2][2][4] = {};
#pragma unroll
  for (int g = 0; g < 8; ++g) {
    float z[2][2][4] = {};
#pragma unroll
    for (int h = 0; h < 8; ++h) {
      float wgh = sW[g][h];
#pragma unroll
      for (int fi = 0; fi < 2; ++fi)
#pragma unroll
        for (int fj = 0; fj < 2; ++fj)
#pragma unroll
          for (int r = 0; r < 4; ++r)
            z[fi][fj][r] = fmaf(acc[h][fi][fj][r], wgh, z[fi][fj][r]);
    }
#pragma unroll
    for (int fi = 0; fi < 2; ++fi)
#pragma unroll
      for (int fj = 0; fj < 2; ++fj)
#pragma unroll
        for (int r = 0; r < 4; ++r) {
          float zz = z[fi][fj][r];
          o[fi][fj][r] += fmaxf(zz, 0.2f * zz);   // leaky relu, slope 0.2
        }
  }

  // ---- write phase: both tiles via LDS -> 1KB-contiguous NT float4 rows.
  // Wave W writes rows 16W..16W+15 (4 KB contiguous region per wave).
  const int a  = tid >> 2;          // tile row 0..63
  const int cb = (tid & 3) * 16;    // 16-float chunk within row

  // (1) direct (bi,bj) tile, row-major staging
  __syncthreads();   // staging bufs dead; safe to alias as lds.t
#pragma unroll
  for (int fi = 0; fi < 2; ++fi)
#pragma unroll
    for (int fj = 0; fj < 2; ++fj)
#pragma unroll
      for (int r = 0; r < 4; ++r) {
        int rr = wr * 32 + fi * 16 + (lane >> 4) * 4 + r;
        int cc = wc * 32 + fj * 16 + (lane & 15);
        lds.t[rr][cc] = o[fi][fj][r];
      }
  __syncthreads();
#pragma unroll
  for (int jj = 0; jj < 4; ++jj) {
    f32x4 v;
#pragma unroll
    for (int e = 0; e < 4; ++e) v[e] = lds.t[a][cb + jj * 4 + e];
    __builtin_nontemporal_store(
        v, reinterpret_cast<f32x4*>(&out[(size_t)(ri0 + a) * NN + ci0 + cb + jj * 4]));
  }

  // (2) mirrored (bj,bi) tile via transpose staging (skip diagonal)
  if (bi != bj) {
    __syncthreads();
#pragma unroll
    for (int fi = 0; fi < 2; ++fi)
#pragma unroll
      for (int fj = 0; fj < 2; ++fj)
#pragma unroll
        for (int r = 0; r < 4; ++r) {
          int rr = wr * 32 + fi * 16 + (lane >> 4) * 4 + r;
          int cc = wc * 32 + fj * 16 + (lane & 15);
          lds.t[cc][rr] = o[fi][fj][r];   // t[c][r] = V(r,c)
        }
    __syncthreads();
#pragma unroll
    for (int jj = 0; jj < 4; ++jj) {
      f32x4 v;
#pragma unroll
      for (int e = 0; e < 4; ++e) v[e] = lds.t[a][cb + jj * 4 + e];
      __builtin_nontemporal_store(
          v, reinterpret_cast<f32x4*>(&out[(size_t)(ci0 + a) * NN + ri0 + cb + jj * 4]));
    }
  }
}

// ---------------------------------------------------------------------------
extern "C" void kernel_launch(void* const* d_in, const int* in_sizes, int n_in,
                              void* d_out, int out_size, void* d_ws, size_t ws_size,
                              hipStream_t stream) {
  const float* vertex = (const float*)d_in[0];   // [4096][1433] f32
  const float* Wvert  = (const float*)d_in[1];   // [512][1433]  f32
  const float* Wattn  = (const float*)d_in[2];   // [8][8]       f32
  float* out = (float*)d_out;                    // [4096][4096] f32

  char* ws = (char*)d_ws;
  ushort* Va = (ushort*)ws;                                           // [4096][1536] bf16
  ushort* Wb = (ushort*)(ws + (size_t)NN * KPAD * 2);                 // [512][1536]  bf16
  ushort* G  = (ushort*)(ws + (size_t)NN * KPAD * 2 + (size_t)CD * KPAD * 2); // [4096][512] bf16

  int tot1 = NN * (KPAD / 8);
  castpad_kernel<<<(tot1 + 255) / 256, 256, 0, stream>>>(vertex, Va, NN, FIN, KPAD);
  int tot2 = CD * (KPAD / 8);
  castpad_kernel<<<(tot2 + 255) / 256, 256, 0, stream>>>(Wvert, Wb, CD, FIN, KPAD);

  gemm1_kernel<<<512, 256, 0, stream>>>(Va, Wb, G);

  int ntri = (NN / 64) * (NN / 64 + 1) / 2;   // 2080
  gram_kernel<<<ntri, 256, 0, stream>>>(G, Wattn, out);
}

// Round 9
// 184.946 us; speedup vs baseline: 1.3246x; 1.3246x over previous
//
#include <hip/hip_runtime.h>
#include <hip/hip_bf16.h>

// Problem constants
#define NN   4096      // nodes
#define FIN  1433      // input features
#define KPAD 1536      // padded K for GEMM1 (12 * 128)
#define NH   8         // heads
#define ND   64        // hidden per head
#define CD   512       // NH*ND

typedef float f32x4 __attribute__((ext_vector_type(4)));
typedef short s16x8 __attribute__((ext_vector_type(8)));   // 8 bf16

#define MFMA16(a, b, c) __builtin_amdgcn_mfma_f32_16x16x32_bf16((a), (b), (c), 0, 0, 0)

__device__ __forceinline__ void gload_lds16(const void* g, void* l) {
  __builtin_amdgcn_global_load_lds((const __attribute__((address_space(1))) void*)g,
                                   (__attribute__((address_space(3))) void*)l, 16, 0, 0);
}

__device__ __forceinline__ ushort f2bf(float x) {
  __hip_bfloat16 b = __float2bfloat16(x);
  ushort u;
  __builtin_memcpy(&u, &b, 2);
  return u;
}

// ---------------------------------------------------------------------------
// Kernel 1: f32 -> bf16 cast with K padding (1433 -> 1536, zero fill).
// ---------------------------------------------------------------------------
__global__ void castpad_kernel(const float* __restrict__ src, ushort* __restrict__ dst,
                               int rows, int kin, int kout) {
  int i = blockIdx.x * blockDim.x + threadIdx.x;   // one 8-elem group
  int kg = kout >> 3;
  int total = rows * kg;
  if (i >= total) return;
  int r  = i / kg;
  int k0 = (i - r * kg) << 3;
  s16x8 v;
#pragma unroll
  for (int j = 0; j < 8; ++j) {
    int k = k0 + j;
    float f = (k < kin) ? src[(size_t)r * kin + k] : 0.0f;
    v[j] = (short)f2bf(f);
  }
  *reinterpret_cast<s16x8*>(&dst[(size_t)r * kout + k0]) = v;
}

// ---------------------------------------------------------------------------
// Kernel 2: GEMM1  g = vertex @ W_vert^T  — unchanged from round 6/7
// (XCD row-band decode, BK=128 double-buffered).
// ---------------------------------------------------------------------------
__global__ __launch_bounds__(256, 2) void gemm1_kernel(const ushort* __restrict__ A,
                                                       const ushort* __restrict__ B,
                                                       ushort* __restrict__ G) {
  __shared__ ushort As[2][64][128];   // 16 KB per buf
  __shared__ ushort Bs[2][64][128];
  const int tid  = threadIdx.x;
  const int lane = tid & 63;
  const int w    = tid >> 6;       // wave 0..3
  const int wr   = w >> 1, wc = w & 1;

  const int b    = blockIdx.x;          // 0..511
  const int x    = b & 7;               // XCD
  const int slot = b >> 3;              // 0..63
  const int by   = x * 8 + (slot >> 3); // row tile 0..63
  const int bx   = slot & 7;            // col tile 0..7
  const int row0 = by * 64;
  const int col0 = bx * 64;

  f32x4 acc[2][2] = {};

  auto stage = [&](int buf, int k0) {
#pragma unroll
    for (int j = 0; j < 4; ++j) {
      int ci = (w * 4 + j) * 64 + lane;
      int r  = ci >> 4;
      int cp = ci & 15;
      int gc = cp ^ (r & 7);
      gload_lds16(A + (size_t)(row0 + r) * KPAD + k0 + gc * 8,
                  &As[buf][0][0] + (size_t)(w * 4 + j) * 512);
      gload_lds16(B + (size_t)(col0 + r) * KPAD + k0 + gc * 8,
                  &Bs[buf][0][0] + (size_t)(w * 4 + j) * 512);
    }
  };

  stage(0, 0);
  __syncthreads();
  int cur = 0;

  for (int k0 = 0; k0 < KPAD; k0 += 128) {
    if (k0 + 128 < KPAD) stage(cur ^ 1, k0 + 128);
#pragma unroll
    for (int kk = 0; kk < 4; ++kk) {
      int kq = kk * 4 + (lane >> 4);
      s16x8 af[2], bfv[2];
#pragma unroll
      for (int f = 0; f < 2; ++f) {
        int ar = wr * 32 + f * 16 + (lane & 15);
        af[f]  = *reinterpret_cast<const s16x8*>(&As[cur][ar][(kq ^ (ar & 7)) * 8]);
        int br = wc * 32 + f * 16 + (lane & 15);
        bfv[f] = *reinterpret_cast<const s16x8*>(&Bs[cur][br][(kq ^ (br & 7)) * 8]);
      }
#pragma unroll
      for (int fi = 0; fi < 2; ++fi)
#pragma unroll
        for (int fj = 0; fj < 2; ++fj)
          acc[fi][fj] = MFMA16(af[fi], bfv[fj], acc[fi][fj]);
    }
    __syncthreads();
    cur ^= 1;
  }

#pragma unroll
  for (int fi = 0; fi < 2; ++fi)
#pragma unroll
    for (int fj = 0; fj < 2; ++fj)
#pragma unroll
      for (int r = 0; r < 4; ++r) {
        int gr = row0 + wr * 32 + fi * 16 + (lane >> 4) * 4 + r;
        int gcol = col0 + wc * 32 + fj * 16 + (lane & 15);
        G[(size_t)gr * CD + gcol] = f2bf(acc[fi][fj][r]);
      }
}

// ---------------------------------------------------------------------------
// Kernel 3: fused Gram + head-mix + lrelu + head-sum.
// Round-7 post-mortem: NT stores with a 64B-STRIDED lane mapping wrote
// 16B per lane per 64B segment -> each partial segment became its own HBM
// burst (WRITE 220 MB = 3.3x). v4 write phase: CONTIGUOUS lane mapping
// (each wave-instr = 1KB contiguous = full 128B lines) + REGULAR stores
// (fully-dirty lines evict as exactly 128B). Direct + transposed mirror
// staged into two LDS buffers at once -> 2 barriers for the whole write.
// ---------------------------------------------------------------------------
__global__ __launch_bounds__(256, 2) void gram_kernel(const ushort* __restrict__ G,
                                                      const float* __restrict__ Wattn,
                                                      float* __restrict__ out) {
  // ---- triangular tile decode with XCD swizzle ----
  const int nwg = (NN / 64) * (NN / 64 + 1) / 2;   // 2080
  const int cpx = nwg / 8;                          // 260
  int b = blockIdx.x;
  int t = (b % 8) * cpx + (b / 8);                  // bijective: 2080 % 8 == 0
  int bi = (int)((129.0f - sqrtf(16641.0f - 8.0f * (float)t)) * 0.5f);
  while ((129 * (bi + 1) - (bi + 1) * (bi + 1)) / 2 <= t) ++bi;
  while ((129 * bi - bi * bi) / 2 > t) --bi;
  const int bj = bi + (t - (129 * bi - bi * bi) / 2);
  const int ri0 = bi * 64, ci0 = bj * 64;

  __shared__ union LdsU {
    struct { ushort A[2][64][128]; ushort B[2][64][128]; } s;  // 4 x 16 KB
    struct { float t1[64][65]; float t2[64][65]; } wbuf;       // 33 KB
  } lds;
  __shared__ float sW[8][8];

  const int tid  = threadIdx.x;
  const int lane = tid & 63;
  const int w    = tid >> 6;
  const int wr   = w >> 1, wc = w & 1;

  if (tid < 64) sW[tid >> 3][tid & 7] = Wattn[tid];

  f32x4 acc[8][2][2] = {};   // [head][fi][fj] — fully static indexing

  // stage heads 2s,2s+1 into buf (16 KB per operand, 4 DMA/thread/operand)
  auto stage = [&](int buf, int s) {
#pragma unroll
    for (int j = 0; j < 4; ++j) {
      int ci = (w * 4 + j) * 64 + lane;   // 0..1023
      int r  = ci >> 4;
      int cp = ci & 15;
      int gc = cp ^ (r & 7);
      gload_lds16(G + (size_t)(ri0 + r) * CD + s * 128 + gc * 8,
                  &lds.s.A[buf][0][0] + (size_t)(w * 4 + j) * 512);
      gload_lds16(G + (size_t)(ci0 + r) * CD + s * 128 + gc * 8,
                  &lds.s.B[buf][0][0] + (size_t)(w * 4 + j) * 512);
    }
  };

  auto compute = [&](int buf, int s) {
#pragma unroll
    for (int hh = 0; hh < 2; ++hh) {
#pragma unroll
      for (int kk = 0; kk < 2; ++kk) {
        int kq = hh * 8 + kk * 4 + (lane >> 4);
        s16x8 af[2], bfv[2];
#pragma unroll
        for (int f = 0; f < 2; ++f) {
          int ar = wr * 32 + f * 16 + (lane & 15);
          af[f]  = *reinterpret_cast<const s16x8*>(
                     &lds.s.A[buf][ar][(kq ^ (ar & 7)) * 8]);
          int br = wc * 32 + f * 16 + (lane & 15);
          bfv[f] = *reinterpret_cast<const s16x8*>(
                     &lds.s.B[buf][br][(kq ^ (br & 7)) * 8]);
        }
        int h = s * 2 + hh;
#pragma unroll
        for (int fi = 0; fi < 2; ++fi)
#pragma unroll
          for (int fj = 0; fj < 2; ++fj)
            acc[h][fi][fj] = MFMA16(af[fi], bfv[fj], acc[h][fi][fj]);
      }
    }
  };

  stage(0, 0);
  __syncthreads();
  int cur = 0;
#pragma unroll
  for (int s = 0; s < 4; ++s) {
    if (s < 3) stage(cur ^ 1, s + 1);   // prefetch overlaps compute
    compute(cur, s);
    __syncthreads();                    // joins + drains prefetch DMA
    cur ^= 1;
  }

  // Epilogue: z_g = sum_h gram_h * W[g][h];  out = sum_g lrelu(z_g)
  float o[2][2][4] = {};
#pragma unroll
  for (int g = 0; g < 8; ++g) {
    float z[2][2][4] = {};
#pragma unroll
    for (int h = 0; h < 8; ++h) {
      float wgh = sW[g][h];
#pragma unroll
      for (int fi = 0; fi < 2; ++fi)
#pragma unroll
        for (int fj = 0; fj < 2; ++fj)
#pragma unroll
          for (int r = 0; r < 4; ++r)
            z[fi][fj][r] = fmaf(acc[h][fi][fj][r], wgh, z[fi][fj][r]);
    }
#pragma unroll
    for (int fi = 0; fi < 2; ++fi)
#pragma unroll
      for (int fj = 0; fj < 2; ++fj)
#pragma unroll
        for (int r = 0; r < 4; ++r) {
          float zz = z[fi][fj][r];
          o[fi][fj][r] += fmaxf(zz, 0.2f * zz);   // leaky relu, slope 0.2
        }
  }

  // ---- write phase: stage BOTH tiles into LDS at once, then store with
  // contiguous lane mapping: thread tid -> row it*16+(tid>>4), 16B chunk
  // (tid&15)*4 floats. Each wave-instruction = 1 KB contiguous.
  const bool mir = (bi != bj);
  // last compute iteration ended with __syncthreads(): staging bufs free
#pragma unroll
  for (int fi = 0; fi < 2; ++fi)
#pragma unroll
    for (int fj = 0; fj < 2; ++fj)
#pragma unroll
      for (int r = 0; r < 4; ++r) {
        int rr = wr * 32 + fi * 16 + (lane >> 4) * 4 + r;
        int cc = wc * 32 + fj * 16 + (lane & 15);
        float v = o[fi][fj][r];
        lds.wbuf.t1[rr][cc] = v;        // row-major (direct tile)
        lds.wbuf.t2[cc][rr] = v;        // transposed (mirror tile)
      }
  __syncthreads();
  const int rsub = tid >> 4;          // 0..15
  const int colf = (tid & 15) * 4;    // f32 column
#pragma unroll
  for (int it = 0; it < 4; ++it) {
    int row = it * 16 + rsub;
    f32x4 v1;
#pragma unroll
    for (int e = 0; e < 4; ++e) v1[e] = lds.wbuf.t1[row][colf + e];
    *reinterpret_cast<f32x4*>(&out[(size_t)(ri0 + row) * NN + ci0 + colf]) = v1;
    if (mir) {
      f32x4 v2;
#pragma unroll
      for (int e = 0; e < 4; ++e) v2[e] = lds.wbuf.t2[row][colf + e];
      *reinterpret_cast<f32x4*>(&out[(size_t)(ci0 + row) * NN + ri0 + colf]) = v2;
    }
  }
}

// ---------------------------------------------------------------------------
extern "C" void kernel_launch(void* const* d_in, const int* in_sizes, int n_in,
                              void* d_out, int out_size, void* d_ws, size_t ws_size,
                              hipStream_t stream) {
  const float* vertex = (const float*)d_in[0];   // [4096][1433] f32
  const float* Wvert  = (const float*)d_in[1];   // [512][1433]  f32
  const float* Wattn  = (const float*)d_in[2];   // [8][8]       f32
  float* out = (float*)d_out;                    // [4096][4096] f32

  char* ws = (char*)d_ws;
  ushort* Va = (ushort*)ws;                                           // [4096][1536] bf16
  ushort* Wb = (ushort*)(ws + (size_t)NN * KPAD * 2);                 // [512][1536]  bf16
  ushort* G  = (ushort*)(ws + (size_t)NN * KPAD * 2 + (size_t)CD * KPAD * 2); // [4096][512] bf16

  int tot1 = NN * (KPAD / 8);
  castpad_kernel<<<(tot1 + 255) / 256, 256, 0, stream>>>(vertex, Va, NN, FIN, KPAD);
  int tot2 = CD * (KPAD / 8);
  castpad_kernel<<<(tot2 + 255) / 256, 256, 0, stream>>>(Wvert, Wb, CD, FIN, KPAD);

  gemm1_kernel<<<512, 256, 0, stream>>>(Va, Wb, G);

  int ntri = (NN / 64) * (NN / 64 + 1) / 2;   // 2080
  gram_kernel<<<ntri, 256, 0, stream>>>(G, Wattn, out);
}